// Round 22
// baseline (342.597 us; speedup 1.0000x reference)
//
#include <hip/hip_runtime.h>
#include <hip/hip_bf16.h>
#include <cstdint>

typedef __bf16 bf16x8 __attribute__((ext_vector_type(8)));
typedef float  f32x4  __attribute__((ext_vector_type(4)));

struct alignas(4) us2 { unsigned short x, y; };
struct alignas(8) us4 { unsigned short x, y, z, w; };

__device__ __forceinline__ unsigned short f2bf(float f) {
    union { float f; unsigned u; } a; a.f = f;
    unsigned r = a.u + 0x7fffu + ((a.u >> 16) & 1u);   // round-to-nearest-even
    return (unsigned short)(r >> 16);
}

__device__ __forceinline__ void gl_lds16(const void* g, void* s) {
    __builtin_amdgcn_global_load_lds(
        (const __attribute__((address_space(1))) void*)g,
        (__attribute__((address_space(3))) void*)s, 16, 0, 0);
}

#define SCHEDB()  __builtin_amdgcn_sched_barrier(0)
#define SBAR()    do { SCHEDB(); __builtin_amdgcn_s_barrier(); SCHEDB(); } while (0)
#define WAITLG(N) do { asm volatile("s_waitcnt lgkmcnt(" #N ")" ::: "memory"); SCHEDB(); } while (0)
#define WAITVM(N) do { asm volatile("s_waitcnt vmcnt(" #N ")" ::: "memory"); SCHEDB(); } while (0)

// C = A(MxK) @ W(NxK)^T, bf16 in, fp32 acc.
// R22: 256x128 tile, 256 threads / 4 waves (2Mx2N), per-wave tile 128x64
// (acc[8][4] unchanged). LDS ring-3 of K-32 half-slots (A 16KB + B 8KB = 24KB)
// = 72KB -> TWO independent blocks/CU. Rationale: the 512-thread monolith
// barrier-aligns both SIMD-resident waves -> LDS bursts and MFMA bursts
// coincide; wall 2775cyc/half vs 1242 MFMA (42% util). Two blocks = two
// independent barrier domains per SIMD -> m114 cross-block MFMA/LDS overlap.
// Per half (R11 free-run body): top WAITVM(6) [certify stage(h), 2-half-old;
// leave stage(h+1) in flight] -> SBAR -> issue 12 ds_reads (aF0-3,bF0-3 first)
// -> stage(h+2) -> WAITLG(4) -> 16 MFMA -> WAITLG(0) -> 16 MFMA.
// Hazards (ring-3, dist-2): reads target slot h; in-flight DMA writes target
// (h+1)%3,(h+2)%3 - disjoint. stage(h+2) overwrites slot read in h-1, ordered
// behind top-of-h barrier.
// Swizzle: R3-proven row-bits[2:1] XOR (0 conflicts measured).
// EPI 0: outb = bf16(gelu_exact(acc+bias)) ; EPI 1: outf = acc+bias ;
// EPI 2: fused coupling, W3 interleaved by 16-col blocks (s-block | t-block).
template<int EPI, int K, int N>
__global__ __launch_bounds__(256, 2)
void gemm256(const unsigned short* __restrict__ A,
             const unsigned short* __restrict__ W,
             const float* __restrict__ bias,
             unsigned short* __restrict__ outb,
             float* __restrict__ outf,
             const float* __restrict__ zin,
             float* __restrict__ ldout)
{
    extern __shared__ char smem[];
    constexpr int NH = K / 32;           // K-32 halves (16 or 64)
    constexpr int GX = N / 128;          // col-blocks of 128

    const int tid  = threadIdx.x;
    const int lane = tid & 63;
    const int wv   = tid >> 6;           // 0..3
    const int wr   = wv >> 1, wc = wv & 1;

    // T1: bijective XCD swizzle (nwg divisible by 8 for all our shapes)
    const int bid = blockIdx.y * GX + blockIdx.x;
    const int nwg = GX * (int)gridDim.y;
    const int swz = (bid & 7) * (nwg >> 3) + (bid >> 3);
    const size_t row0 = (size_t)(swz / GX) * 256;
    const size_t col0 = (size_t)(swz % GX) * 128;

    // LDS: A ring = 3 x 16KB at +0 ; B ring = 3 x 8KB at +49152.
    // Half-slot rows x 64B; chunk c: row c>>2, pos c&3, holds src k-chunk
    // (c&3) ^ ((row>>1)&3)  [R3 swizzle]. Thread tid stages chunk j*256+tid
    // (row = j*64 + (tid>>2); +64 preserves row bits[2:1]).
    const int cse = (((tid & 3) ^ ((tid >> 3) & 3)) << 3);  // src elem offset
    const unsigned short* ag = A + (row0 + (tid >> 2)) * (size_t)K + cse;
    const unsigned short* bg = W + (col0 + (tid >> 2)) * (size_t)K + cse;

    auto stage = [&](int hh, int sl) {   // 6 gl_lds: A j=0..3, B j=0..1
        char* dA = smem + sl * 16384 + tid * 16;
        char* dB = smem + 49152 + sl * 8192 + tid * 16;
        const unsigned short* a = ag + (size_t)hh * 32;
        const unsigned short* b = bg + (size_t)hh * 32;
        gl_lds16(a,                    dA);
        gl_lds16(a + (size_t) 64 * K,  dA + 4096);
        gl_lds16(a + (size_t)128 * K,  dA + 8192);
        gl_lds16(a + (size_t)192 * K,  dA + 12288);
        gl_lds16(b,                    dB);
        gl_lds16(b + (size_t) 64 * K,  dB + 4096);
    };

    // fragment reads: byte = row*64 + ((lane>>4) ^ ((row>>1)&3))*16
    const int ln15 = lane & 15;
    const int xo   = (((lane >> 4) ^ ((ln15 >> 1) & 3)) << 4);
    const int arow = wr * 128 + ln15;                       // + mi*16 (mi 0..7)
    const int brow = wc * 64 + ln15;                        // + nf*16 (nf 0..3)

#define LDA(sl, row) (*(const bf16x8*)(smem + (sl) * 16384 + (size_t)(row) * 64 + xo))
#define LDB(sl, row) (*(const bf16x8*)(smem + 49152 + (sl) * 8192 + (size_t)(row) * 64 + xo))

    f32x4 acc[8][4] = {};

    // prologue: stage halves 0,1 into slots 0,1 (12 loads in flight)
    stage(0, 0); stage(1, 1);

    int sl = 0;                          // h % 3, maintained incrementally
    for (int h = 0; h < NH; ++h) {
        // certify stage(h) (2-half-old, stale); keep stage(h+1) in flight
        if (h < NH - 1) WAITVM(6);
        else            WAITVM(0);
        SBAR();

        bf16x8 aF[8], bF[4];
        // group 1 first (aF0-3 + bF0-3) so WAITLG(4) certifies exactly them
#pragma unroll
        for (int mf = 0; mf < 4; ++mf) aF[mf] = LDA(sl, arow + mf * 16);
#pragma unroll
        for (int nf = 0; nf < 4; ++nf) bF[nf] = LDB(sl, brow + nf * 16);
        SCHEDB();
#pragma unroll
        for (int mf = 4; mf < 8; ++mf) aF[mf] = LDA(sl, arow + mf * 16);
        SCHEDB();
        {
            int sl2 = sl + 2; if (sl2 >= 3) sl2 -= 3;
            if (h + 2 < NH) stage(h + 2, sl2);
        }

        WAITLG(4);                       // aF0-3+bF0-3 certified; aF4-7 float
        __builtin_amdgcn_s_setprio(1);
#pragma unroll
        for (int mf = 0; mf < 4; ++mf)
#pragma unroll
            for (int nf = 0; nf < 4; ++nf)
                acc[mf][nf] = __builtin_amdgcn_mfma_f32_16x16x32_bf16(
                    aF[mf], bF[nf], acc[mf][nf], 0, 0, 0);
        __builtin_amdgcn_s_setprio(0);

        WAITLG(0);                       // aF4-7 certified
        __builtin_amdgcn_s_setprio(1);
#pragma unroll
        for (int mf = 4; mf < 8; ++mf)
#pragma unroll
            for (int nf = 0; nf < 4; ++nf)
                acc[mf][nf] = __builtin_amdgcn_mfma_f32_16x16x32_bf16(
                    aF[mf], bF[nf], acc[mf][nf], 0, 0, 0);
        __builtin_amdgcn_s_setprio(0);

        ++sl; if (sl == 3) sl = 0;
    }
#undef LDA
#undef LDB

    // epilogue: D layout col = lane&15, row = (lane>>4)*4 + reg
    const int lq = lane >> 4;
    float bv[4];
#pragma unroll
    for (int nf = 0; nf < 4; ++nf) bv[nf] = bias[col0 + wc * 64 + nf * 16 + ln15];

    if (EPI == 2) {
        // W interleaved by 16-col blocks: nf=2p -> s, nf=2p+1 -> t, same j.
        const float2* zin2 = (const float2*)zin;
        float2*       out2 = (float2*)outf;
#pragma unroll
        for (int mi = 0; mi < 8; ++mi) {
#pragma unroll
            for (int r = 0; r < 4; ++r) {
                const size_t row = row0 + wr * 128 + mi * 16 + lq * 4 + r;
                float sv = 0.f;
#pragma unroll
                for (int p = 0; p < 2; ++p) {
                    float s = acc[mi][2 * p][r] + bv[2 * p];
                    float t = acc[mi][2 * p + 1][r] + bv[2 * p + 1];
                    const size_t j = (col0 >> 1) + wc * 32 + p * 16 + ln15;
                    float2 zv = zin2[row * 512 + j];
                    float2 o; o.x = zv.x; o.y = zv.y * __expf(s) + t;
                    out2[row * 512 + j] = o;
                    sv += s;
                }
                sv += __shfl_xor(sv, 1, 64);
                sv += __shfl_xor(sv, 2, 64);
                sv += __shfl_xor(sv, 4, 64);
                sv += __shfl_xor(sv, 8, 64);
                if (ln15 == 0) atomicAdd(&ldout[row], sv);
            }
        }
    } else {
#pragma unroll
        for (int mi = 0; mi < 8; ++mi) {
#pragma unroll
            for (int r = 0; r < 4; ++r) {
                const size_t row = row0 + wr * 128 + mi * 16 + lq * 4 + r;
#pragma unroll
                for (int nf = 0; nf < 4; ++nf) {
                    const size_t col = col0 + wc * 64 + nf * 16 + ln15;
                    float v = acc[mi][nf][r] + bv[nf];
                    if (EPI == 0) {
                        float g = 0.5f * v * (1.0f + erff(v * 0.70710678118654752f));
                        outb[row * N + col] = f2bf(g);
                    } else {
                        outf[row * N + col] = v;
                    }
                }
            }
        }
    }
}

// One fused prep pass: W1/W2 cvt, W3 interleave-by-16 cvt, pack_even, b3i, ldout.
__global__ void prep_all(const float* __restrict__ W1, const float* __restrict__ W2,
                         const float* __restrict__ W3, const float* __restrict__ b3,
                         const float* __restrict__ z,  const float* __restrict__ ld,
                         unsigned short* __restrict__ w1b, unsigned short* __restrict__ w2b,
                         unsigned short* __restrict__ w3i, float* __restrict__ b3i,
                         unsigned short* __restrict__ zm,  float* __restrict__ ldout)
{
    constexpr int N1 = 2048 * 512 / 4;
    constexpr int N2 = 2048 * 2048 / 4;
    constexpr int N3 = 1024 * 2048 / 4;
    constexpr int N4 = 16384 * 1024 / 4;
    constexpr int N5 = 1024;
    constexpr int N6 = 16384;
    constexpr int TOT = N1 + N2 + N3 + N4 + N5 + N6;
    const int stride = gridDim.x * blockDim.x;
    for (int i = blockIdx.x * blockDim.x + threadIdx.x; i < TOT; i += stride) {
        int j = i;
        if (j < N1) {
            float4 v = ((const float4*)W1)[j];
            ((us4*)w1b)[j] = us4{ f2bf(v.x), f2bf(v.y), f2bf(v.z), f2bf(v.w) };
            continue;
        }
        j -= N1;
        if (j < N2) {
            float4 v = ((const float4*)W2)[j];
            ((us4*)w2b)[j] = us4{ f2bf(v.x), f2bf(v.y), f2bf(v.z), f2bf(v.w) };
            continue;
        }
        j -= N2;
        if (j < N3) {
            int row = j >> 9, c4 = j & 511;
            int q = row >> 5, u = row & 31;
            int srcrow = (u < 16) ? (q * 16 + u) : (512 + q * 16 + u - 16);
            float4 v = ((const float4*)W3)[(size_t)srcrow * 512 + c4];
            ((us4*)w3i)[j] = us4{ f2bf(v.x), f2bf(v.y), f2bf(v.z), f2bf(v.w) };
            continue;
        }
        j -= N3;
        if (j < N4) {
            float4 v = ((const float4*)z)[j];
            ((us2*)zm)[j] = us2{ f2bf(v.x), f2bf(v.z) };
            continue;
        }
        j -= N4;
        if (j < N5) {
            int q = j >> 5, u = j & 31;
            b3i[j] = b3[(u < 16) ? (q * 16 + u) : (512 + q * 16 + u - 16)];
            continue;
        }
        j -= N5;
        ldout[j] = ld[j];
    }
}

extern "C" void kernel_launch(void* const* d_in, const int* in_sizes, int n_in,
                              void* d_out, int out_size, void* d_ws, size_t ws_size,
                              hipStream_t stream)
{
    const float* z  = (const float*)d_in[0];
    const float* ld = (const float*)d_in[1];
    const float* W1 = (const float*)d_in[2];
    const float* b1 = (const float*)d_in[3];
    const float* W2 = (const float*)d_in[4];
    const float* b2 = (const float*)d_in[5];
    const float* W3 = (const float*)d_in[6];
    const float* b3 = (const float*)d_in[7];

    float* out   = (float*)d_out;
    float* zout  = out;
    float* ldout = out + (size_t)16384 * 1024;

    char* w = (char*)d_ws;
    unsigned short* zm  = (unsigned short*)w; w += (size_t)16384 * 512 * 2;
    unsigned short* w1b = (unsigned short*)w; w += (size_t)2048 * 512 * 2;
    unsigned short* w2b = (unsigned short*)w; w += (size_t)2048 * 2048 * 2;
    unsigned short* w3i = (unsigned short*)w; w += (size_t)1024 * 2048 * 2;
    unsigned short* h1  = (unsigned short*)w; w += (size_t)16384 * 2048 * 2;
    unsigned short* h2  = (unsigned short*)w; w += (size_t)16384 * 2048 * 2;
    float*          b3i = (float*)w;          w += 1024 * 4;

    (void)hipFuncSetAttribute((const void*)&gemm256<0, 512,  2048>,
                              hipFuncAttributeMaxDynamicSharedMemorySize, 73728);
    (void)hipFuncSetAttribute((const void*)&gemm256<0, 2048, 2048>,
                              hipFuncAttributeMaxDynamicSharedMemorySize, 73728);
    (void)hipFuncSetAttribute((const void*)&gemm256<2, 2048, 1024>,
                              hipFuncAttributeMaxDynamicSharedMemorySize, 73728);

    prep_all<<<2048, 256, 0, stream>>>(W1, W2, W3, b3, z, ld,
                                       w1b, w2b, w3i, b3i, zm, ldout);

    gemm256<0, 512,  2048><<<dim3(16, 64), 256, 73728, stream>>>(zm, w1b, b1, h1, nullptr, nullptr, nullptr);
    gemm256<0, 2048, 2048><<<dim3(16, 64), 256, 73728, stream>>>(h1, w2b, b2, h2, nullptr, nullptr, nullptr);
    gemm256<2, 2048, 1024><<<dim3(8, 64),  256, 73728, stream>>>(h2, w3i, b3i, nullptr, zout, z, ldout);
}

// Round 23
// 307.381 us; speedup vs baseline: 1.1146x; 1.1146x over previous
//
#include <hip/hip_runtime.h>
#include <hip/hip_bf16.h>
#include <cstdint>

typedef __bf16 bf16x8 __attribute__((ext_vector_type(8)));
typedef float  f32x4  __attribute__((ext_vector_type(4)));

struct alignas(4) us2 { unsigned short x, y; };
struct alignas(8) us4 { unsigned short x, y, z, w; };

__device__ __forceinline__ unsigned short f2bf(float f) {
    union { float f; unsigned u; } a; a.f = f;
    unsigned r = a.u + 0x7fffu + ((a.u >> 16) & 1u);   // round-to-nearest-even
    return (unsigned short)(r >> 16);
}

__device__ __forceinline__ void gl_lds16(const void* g, void* s) {
    __builtin_amdgcn_global_load_lds(
        (const __attribute__((address_space(1))) void*)g,
        (__attribute__((address_space(3))) void*)s, 16, 0, 0);
}

#define SCHEDB()  __builtin_amdgcn_sched_barrier(0)
#define SBAR()    do { SCHEDB(); __builtin_amdgcn_s_barrier(); SCHEDB(); } while (0)
#define WAITLG(N) do { asm volatile("s_waitcnt lgkmcnt(" #N ")" ::: "memory"); SCHEDB(); } while (0)
#define WAITVM(N) do { asm volatile("s_waitcnt vmcnt(" #N ")" ::: "memory"); SCHEDB(); } while (0)

// C = A(MxK) @ W(NxK)^T, bf16 in, fp32 acc. 256x256 tile, 8 waves (2Mx4N).
// FINAL (session-best R15, measured 316.06/318.49us):
// R13 deep read pipeline + period-2 register ping-pong.
// Ring of 4 K-32 half-slots (A 16KB + B 16KB, 128KB). Stage h+3 during h.
// Per half: WAITVM(4) [certify thru stage(h+1)] -> SBAR -> issue aH(4) ->
// WAITLG(4) [pA/pB ready, aH floats] -> 16 MFMA -> prefetch nA/nB(8, slot h+1)
// + stage(h+3) -> WAITLG(8) [aH ready, prefetch floats] -> 16 MFMA.
// Hazard (ring-4): in-flight reads target slots h,h+1; DMA writes (h+2),(h+3).
// Swizzle: R3-proven row-bits[2:1] XOR (0 conflicts measured).
// Refuted directions (22 rounds): 32x32x16 MFMA (R18/R19 4-way conflicts),
// 2 blocks/CU via big tile (R6/R12 spill) or small tile (R22: no TLP gain),
// split coupling epilogue (R20 +14us), x4 unroll (R14 spill), m201 phase
// template single-lever port (R17 regressed; combo-only per m218/m230).
// EPI 0: outb = bf16(gelu_exact(acc+bias)) ; EPI 1: outf = acc+bias ;
// EPI 2: fused coupling, W3 interleaved by 16-col blocks (s-block | t-block).
template<int EPI, int K, int N>
__global__ __launch_bounds__(512, 2)
void gemm256(const unsigned short* __restrict__ A,
             const unsigned short* __restrict__ W,
             const float* __restrict__ bias,
             unsigned short* __restrict__ outb,
             float* __restrict__ outf,
             const float* __restrict__ zin,
             float* __restrict__ ldout)
{
    extern __shared__ char smem[];
    constexpr int NH = K / 32;           // number of K-32 halves (16 or 64)
    constexpr int GX = N / 256;
    static_assert(NH % 2 == 0, "ping-pong unroll");

    const int tid  = threadIdx.x;
    const int lane = tid & 63;
    const int wv   = tid >> 6;           // 0..7
    const int wr   = wv >> 2, wc = wv & 3;

    // T1: bijective XCD swizzle (nwg divisible by 8 for all our shapes)
    const int bid = blockIdx.y * GX + blockIdx.x;
    const int nwg = GX * (int)gridDim.y;
    const int swz = (bid & 7) * (nwg >> 3) + (bid >> 3);
    const size_t row0 = (size_t)(swz / GX) * 256;
    const size_t col0 = (size_t)(swz % GX) * 256;

    // LDS: A ring = 4 x 16KB at +0 ; B ring = 4 x 16KB at +65536.
    // Half-slot: 256 rows x 64B. Chunk c (16B): row c>>2, pos c&3, holds
    // src k-chunk (c&3) ^ ((row>>1)&3)   [R3 swizzle, 0-conflict]
    const int cse = (((tid & 3) ^ ((tid >> 3) & 3)) << 3);  // src elem offset
    const unsigned short* ag = A + (row0 + (tid >> 2)) * (size_t)K + cse;
    const unsigned short* bg = W + (col0 + (tid >> 2)) * (size_t)K + cse;

    auto stage = [&](int hh) {           // 4 x gl_lds (A j0,j1 ; B j0,j1)
        char* dA = smem + (hh & 3) * 16384 + tid * 16;
        char* dB = dA + 65536;
        const unsigned short* a = ag + (size_t)hh * 32;
        const unsigned short* b = bg + (size_t)hh * 32;
        gl_lds16(a,                     dA);
        gl_lds16(a + (size_t)128 * K,   dA + 8192);
        gl_lds16(b,                     dB);
        gl_lds16(b + (size_t)128 * K,   dB + 8192);
    };

    // fragment reads: byte = row*64 + ((lane>>4) ^ ((row>>1)&3))*16
    const int ln15 = lane & 15;
    const int xo   = (((lane >> 4) ^ ((ln15 >> 1) & 3)) << 4);
    const int arow = wr * 128 + ln15;                       // + mi*16 (mi 0..7)
    const int brow = wc * 64 + ln15;                        // + nf*16 (nf 0..3)

#define LD(base, row) (*(const bf16x8*)((base) + (size_t)(row) * 64 + xo))

    f32x4 acc[8][4] = {};
    bf16x8 A0[4], B0[4], A1[4], B1[4], aH[4];

    // prologue: stage halves 0,1,2 ; certify stage(0) ; prefetch slot-0 quad-1
    stage(0); stage(1); stage(2);
    WAITVM(8);                           // stage(0) landed (1,2 in flight)
    SBAR();
#pragma unroll
    for (int mf = 0; mf < 4; ++mf) A0[mf] = LD(smem, arow + mf * 16);
#pragma unroll
    for (int nf = 0; nf < 4; ++nf) B0[nf] = LD(smem + 65536, brow + nf * 16);

    // one K-32 half: consume (pA,pB) on slot h, prefetch (nA,nB) from slot h+1
    auto half_body = [&](int h, bf16x8 (&pA)[4], bf16x8 (&pB)[4],
                         bf16x8 (&nA)[4], bf16x8 (&nB)[4]) {
        const char* cA  = smem + (h & 3) * 16384;
        const char* cB  = cA + 65536;
        const char* cAn = smem + ((h + 1) & 3) * 16384;
        const char* cBn = cAn + 65536;

        // top-of-half: certify through stage(h+1) (counted), then barrier
        if (h <= NH - 3) WAITVM(4);
        else             WAITVM(0);
        SBAR();

        // issue aH (slot h, rows 64..127); pA/pB in flight/landed
#pragma unroll
        for (int mf = 0; mf < 4; ++mf) aH[mf] = LD(cA, arow + 64 + mf * 16);
        WAITLG(4);                       // pA,pB certified; aH floats
        __builtin_amdgcn_s_setprio(1);
#pragma unroll
        for (int mf = 0; mf < 4; ++mf)
#pragma unroll
            for (int nf = 0; nf < 4; ++nf)
                acc[mf][nf] = __builtin_amdgcn_mfma_f32_16x16x32_bf16(
                    pA[mf], pB[nf], acc[mf][nf], 0, 0, 0);
        __builtin_amdgcn_s_setprio(0);

        // prefetch next half's quadrant-1 (slot h+1) + stage h+3
        if (h + 1 < NH) {
#pragma unroll
            for (int mf = 0; mf < 4; ++mf) nA[mf] = LD(cAn, arow + mf * 16);
#pragma unroll
            for (int nf = 0; nf < 4; ++nf) nB[nf] = LD(cBn, brow + nf * 16);
            SCHEDB();
        }
        if (h + 3 < NH) stage(h + 3);

        if (h + 1 < NH) WAITLG(8);       // aH certified; nA/nB float
        else            WAITLG(0);
        __builtin_amdgcn_s_setprio(1);
#pragma unroll
        for (int mf = 0; mf < 4; ++mf)
#pragma unroll
            for (int nf = 0; nf < 4; ++nf)
                acc[mf + 4][nf] = __builtin_amdgcn_mfma_f32_16x16x32_bf16(
                    aH[mf], pB[nf], acc[mf + 4][nf], 0, 0, 0);
        __builtin_amdgcn_s_setprio(0);
    };

    for (int h = 0; h < NH; h += 2) {
        half_body(h,     A0, B0, A1, B1);   // consume set0, fill set1
        half_body(h + 1, A1, B1, A0, B0);   // consume set1, fill set0
    }
#undef LD

    // epilogue: D layout col = lane&15, row = (lane>>4)*4 + reg
    const int lq = lane >> 4;
    float bv[4];
#pragma unroll
    for (int nf = 0; nf < 4; ++nf) bv[nf] = bias[col0 + wc * 64 + nf * 16 + ln15];

    if (EPI == 2) {
        // W interleaved by 16-col blocks: nf=2p -> s, nf=2p+1 -> t, same j.
        const float2* zin2 = (const float2*)zin;
        float2*       out2 = (float2*)outf;
#pragma unroll
        for (int mi = 0; mi < 8; ++mi) {
#pragma unroll
            for (int r = 0; r < 4; ++r) {
                const size_t row = row0 + wr * 128 + mi * 16 + lq * 4 + r;
                float sv = 0.f;
#pragma unroll
                for (int p = 0; p < 2; ++p) {
                    float s = acc[mi][2 * p][r] + bv[2 * p];
                    float t = acc[mi][2 * p + 1][r] + bv[2 * p + 1];
                    const size_t j = (col0 >> 1) + wc * 32 + p * 16 + ln15;
                    float2 zv = zin2[row * 512 + j];
                    float2 o; o.x = zv.x; o.y = zv.y * __expf(s) + t;
                    out2[row * 512 + j] = o;
                    sv += s;
                }
                sv += __shfl_xor(sv, 1, 64);
                sv += __shfl_xor(sv, 2, 64);
                sv += __shfl_xor(sv, 4, 64);
                sv += __shfl_xor(sv, 8, 64);
                if (ln15 == 0) atomicAdd(&ldout[row], sv);
            }
        }
    } else {
#pragma unroll
        for (int mi = 0; mi < 8; ++mi) {
#pragma unroll
            for (int r = 0; r < 4; ++r) {
                const size_t row = row0 + wr * 128 + mi * 16 + lq * 4 + r;
#pragma unroll
                for (int nf = 0; nf < 4; ++nf) {
                    const size_t col = col0 + wc * 64 + nf * 16 + ln15;
                    float v = acc[mi][nf][r] + bv[nf];
                    if (EPI == 0) {
                        float g = 0.5f * v * (1.0f + erff(v * 0.70710678118654752f));
                        outb[row * N + col] = f2bf(g);
                    } else {
                        outf[row * N + col] = v;
                    }
                }
            }
        }
    }
}

// One fused prep pass: W1/W2 cvt, W3 interleave-by-16 cvt, pack_even, b3i, ldout.
__global__ void prep_all(const float* __restrict__ W1, const float* __restrict__ W2,
                         const float* __restrict__ W3, const float* __restrict__ b3,
                         const float* __restrict__ z,  const float* __restrict__ ld,
                         unsigned short* __restrict__ w1b, unsigned short* __restrict__ w2b,
                         unsigned short* __restrict__ w3i, float* __restrict__ b3i,
                         unsigned short* __restrict__ zm,  float* __restrict__ ldout)
{
    constexpr int N1 = 2048 * 512 / 4;
    constexpr int N2 = 2048 * 2048 / 4;
    constexpr int N3 = 1024 * 2048 / 4;
    constexpr int N4 = 16384 * 1024 / 4;
    constexpr int N5 = 1024;
    constexpr int N6 = 16384;
    constexpr int TOT = N1 + N2 + N3 + N4 + N5 + N6;
    const int stride = gridDim.x * blockDim.x;
    for (int i = blockIdx.x * blockDim.x + threadIdx.x; i < TOT; i += stride) {
        int j = i;
        if (j < N1) {
            float4 v = ((const float4*)W1)[j];
            ((us4*)w1b)[j] = us4{ f2bf(v.x), f2bf(v.y), f2bf(v.z), f2bf(v.w) };
            continue;
        }
        j -= N1;
        if (j < N2) {
            float4 v = ((const float4*)W2)[j];
            ((us4*)w2b)[j] = us4{ f2bf(v.x), f2bf(v.y), f2bf(v.z), f2bf(v.w) };
            continue;
        }
        j -= N2;
        if (j < N3) {
            int row = j >> 9, c4 = j & 511;
            int q = row >> 5, u = row & 31;
            int srcrow = (u < 16) ? (q * 16 + u) : (512 + q * 16 + u - 16);
            float4 v = ((const float4*)W3)[(size_t)srcrow * 512 + c4];
            ((us4*)w3i)[j] = us4{ f2bf(v.x), f2bf(v.y), f2bf(v.z), f2bf(v.w) };
            continue;
        }
        j -= N3;
        if (j < N4) {
            float4 v = ((const float4*)z)[j];
            ((us2*)zm)[j] = us2{ f2bf(v.x), f2bf(v.z) };
            continue;
        }
        j -= N4;
        if (j < N5) {
            int q = j >> 5, u = j & 31;
            b3i[j] = b3[(u < 16) ? (q * 16 + u) : (512 + q * 16 + u - 16)];
            continue;
        }
        j -= N5;
        ldout[j] = ld[j];
    }
}

extern "C" void kernel_launch(void* const* d_in, const int* in_sizes, int n_in,
                              void* d_out, int out_size, void* d_ws, size_t ws_size,
                              hipStream_t stream)
{
    const float* z  = (const float*)d_in[0];
    const float* ld = (const float*)d_in[1];
    const float* W1 = (const float*)d_in[2];
    const float* b1 = (const float*)d_in[3];
    const float* W2 = (const float*)d_in[4];
    const float* b2 = (const float*)d_in[5];
    const float* W3 = (const float*)d_in[6];
    const float* b3 = (const float*)d_in[7];

    float* out   = (float*)d_out;
    float* zout  = out;
    float* ldout = out + (size_t)16384 * 1024;

    char* w = (char*)d_ws;
    unsigned short* zm  = (unsigned short*)w; w += (size_t)16384 * 512 * 2;
    unsigned short* w1b = (unsigned short*)w; w += (size_t)2048 * 512 * 2;
    unsigned short* w2b = (unsigned short*)w; w += (size_t)2048 * 2048 * 2;
    unsigned short* w3i = (unsigned short*)w; w += (size_t)1024 * 2048 * 2;
    unsigned short* h1  = (unsigned short*)w; w += (size_t)16384 * 2048 * 2;
    unsigned short* h2  = (unsigned short*)w; w += (size_t)16384 * 2048 * 2;
    float*          b3i = (float*)w;          w += 1024 * 4;

    (void)hipFuncSetAttribute((const void*)&gemm256<0, 512,  2048>,
                              hipFuncAttributeMaxDynamicSharedMemorySize, 131072);
    (void)hipFuncSetAttribute((const void*)&gemm256<0, 2048, 2048>,
                              hipFuncAttributeMaxDynamicSharedMemorySize, 131072);
    (void)hipFuncSetAttribute((const void*)&gemm256<2, 2048, 1024>,
                              hipFuncAttributeMaxDynamicSharedMemorySize, 131072);

    prep_all<<<2048, 256, 0, stream>>>(W1, W2, W3, b3, z, ld,
                                       w1b, w2b, w3i, b3i, zm, ldout);

    gemm256<0, 512,  2048><<<dim3(8, 64), 512, 131072, stream>>>(zm, w1b, b1, h1, nullptr, nullptr, nullptr);
    gemm256<0, 2048, 2048><<<dim3(8, 64), 512, 131072, stream>>>(h1, w2b, b2, h2, nullptr, nullptr, nullptr);
    gemm256<2, 2048, 1024><<<dim3(4, 64), 512, 131072, stream>>>(h2, w3i, b3i, nullptr, zout, z, ldout);
}

// Round 24
// 291.602 us; speedup vs baseline: 1.1749x; 1.0541x over previous
//
#include <hip/hip_runtime.h>
#include <hip/hip_bf16.h>
#include <cstdint>

typedef __bf16 bf16x8 __attribute__((ext_vector_type(8)));
typedef float  f32x4  __attribute__((ext_vector_type(4)));

struct alignas(4) us2 { unsigned short x, y; };
struct alignas(8) us4 { unsigned short x, y, z, w; };

__device__ __forceinline__ unsigned short f2bf(float f) {
    union { float f; unsigned u; } a; a.f = f;
    unsigned r = a.u + 0x7fffu + ((a.u >> 16) & 1u);   // round-to-nearest-even
    return (unsigned short)(r >> 16);
}

__device__ __forceinline__ void gl_lds16(const void* g, void* s) {
    __builtin_amdgcn_global_load_lds(
        (const __attribute__((address_space(1))) void*)g,
        (__attribute__((address_space(3))) void*)s, 16, 0, 0);
}

#define SCHEDB()  __builtin_amdgcn_sched_barrier(0)
#define SBAR()    do { SCHEDB(); __builtin_amdgcn_s_barrier(); SCHEDB(); } while (0)
#define WAITLG(N) do { asm volatile("s_waitcnt lgkmcnt(" #N ")" ::: "memory"); SCHEDB(); } while (0)
#define WAITVM(N) do { asm volatile("s_waitcnt vmcnt(" #N ")" ::: "memory"); SCHEDB(); } while (0)

// C = A(MxK) @ W(NxK)^T, bf16 in, fp32 acc. 256x256 tile.
// R24: 1024 threads / 16 waves (4Mx4N), wave-tile 64x64, acc[4][4] (64 AGPR).
// Rationale: 16 waves x ~115 regs fits the 2048-reg CU file -> 4 waves/SIMD
// (double the locked R15 config's 2) -> TLP covers ds_read latency, barrier
// convergence and MFMA dependency gaps (m97/m114 mechanism) instead of
// hand-scheduled ILP which capped at 42% MfmaUtil across 14 variants.
// Per-SIMD MFMA floor unchanged (4w x 16 MFMA/half); LDS traffic/half 128KB
// (667cyc) still under the 1242cyc MFMA floor.
// Ring of 4 K-32 half-slots (A 16KB + B 16KB, 128KB). Stage h+3 during h
// (2 gl_lds/thread-block-half; 1024 thr x 16B = 16KB covers a half-slot).
// Per half: ladder WAITVM(4/2/0) [certify stage(h); counted, never drains in
// steady state] -> SBAR -> 8 ds_reads (aF01,bF0-3 | aF23) -> stage(h+3) ->
// WAITLG(2) -> 8 MFMA -> WAITLG(0) -> 8 MFMA.
// Swizzle: R3-proven row-bits[2:1] XOR (0 conflicts measured).
// EPI 0: outb = bf16(gelu_exact(acc+bias)) ; EPI 1: outf = acc+bias ;
// EPI 2: fused coupling, W3 interleaved by 16-col blocks (s-block | t-block).
template<int EPI, int K, int N>
__global__ __launch_bounds__(1024)
void gemm256(const unsigned short* __restrict__ A,
             const unsigned short* __restrict__ W,
             const float* __restrict__ bias,
             unsigned short* __restrict__ outb,
             float* __restrict__ outf,
             const float* __restrict__ zin,
             float* __restrict__ ldout)
{
    extern __shared__ char smem[];
    constexpr int NH = K / 32;           // number of K-32 halves (16 or 64)
    constexpr int GX = N / 256;

    const int tid  = threadIdx.x;
    const int lane = tid & 63;
    const int wv   = tid >> 6;           // 0..15
    const int wr   = wv >> 2, wc = wv & 3;

    // T1: bijective XCD swizzle (nwg divisible by 8 for all our shapes)
    const int bid = blockIdx.y * GX + blockIdx.x;
    const int nwg = GX * (int)gridDim.y;
    const int swz = (bid & 7) * (nwg >> 3) + (bid >> 3);
    const size_t row0 = (size_t)(swz / GX) * 256;
    const size_t col0 = (size_t)(swz % GX) * 256;

    // LDS: A ring = 4 x 16KB at +0 ; B ring = 4 x 16KB at +65536.
    // Half-slot: 256 rows x 64B. Chunk c (16B): row c>>2, pos c&3, holds
    // src k-chunk (c&3) ^ ((row>>1)&3)   [R3 swizzle, 0-conflict]
    const int cse = (((tid & 3) ^ ((tid >> 3) & 3)) << 3);  // src elem offset
    const unsigned short* ag = A + (row0 + (tid >> 2)) * (size_t)K + cse;
    const unsigned short* bg = W + (col0 + (tid >> 2)) * (size_t)K + cse;

    auto stage = [&](int hh) {           // 2 x gl_lds (full A + B half-slots)
        char* dA = smem + (hh & 3) * 16384 + tid * 16;
        char* dB = dA + 65536;
        gl_lds16(ag + (size_t)hh * 32, dA);
        gl_lds16(bg + (size_t)hh * 32, dB);
    };

    // fragment reads: byte = row*64 + ((lane>>4) ^ ((row>>1)&3))*16
    const int ln15 = lane & 15;
    const int xo   = (((lane >> 4) ^ ((ln15 >> 1) & 3)) << 4);
    const int arow = wr * 64 + ln15;                        // + mi*16 (mi 0..3)
    const int brow = wc * 64 + ln15;                        // + nf*16 (nf 0..3)

#define LD(base, row) (*(const bf16x8*)((base) + (size_t)(row) * 64 + xo))

    f32x4 acc[4][4] = {};

    // prologue: stage halves 0,1,2 (6 loads in flight)
    stage(0); stage(1); stage(2);

    for (int h = 0; h < NH; ++h) {
        const char* cA = smem + (h & 3) * 16384;
        const char* cB = cA + 65536;

        // top-of-half: certify stage(h) (counted; leaves h+1,h+2 in flight)
        if (h <= NH - 3)      WAITVM(4);
        else if (h == NH - 2) WAITVM(2);
        else                  WAITVM(0);
        SBAR();

        bf16x8 aF[4], bF[4];
        // group 1: aF0,1 + bF0-3 (6 reads) ; group 2: aF2,3
        aF[0] = LD(cA, arow);
        aF[1] = LD(cA, arow + 16);
#pragma unroll
        for (int nf = 0; nf < 4; ++nf) bF[nf] = LD(cB, brow + nf * 16);
        SCHEDB();
        aF[2] = LD(cA, arow + 32);
        aF[3] = LD(cA, arow + 48);
        SCHEDB();
        if (h + 3 < NH) stage(h + 3);

        WAITLG(2);                       // aF0,1+bF0-3 certified; aF2,3 float
        __builtin_amdgcn_s_setprio(1);
#pragma unroll
        for (int mf = 0; mf < 2; ++mf)
#pragma unroll
            for (int nf = 0; nf < 4; ++nf)
                acc[mf][nf] = __builtin_amdgcn_mfma_f32_16x16x32_bf16(
                    aF[mf], bF[nf], acc[mf][nf], 0, 0, 0);
        __builtin_amdgcn_s_setprio(0);

        WAITLG(0);                       // aF2,3 certified
        __builtin_amdgcn_s_setprio(1);
#pragma unroll
        for (int mf = 2; mf < 4; ++mf)
#pragma unroll
            for (int nf = 0; nf < 4; ++nf)
                acc[mf][nf] = __builtin_amdgcn_mfma_f32_16x16x32_bf16(
                    aF[mf], bF[nf], acc[mf][nf], 0, 0, 0);
        __builtin_amdgcn_s_setprio(0);
    }
#undef LD

    // epilogue: D layout col = lane&15, row = (lane>>4)*4 + reg
    const int lq = lane >> 4;
    float bv[4];
#pragma unroll
    for (int nf = 0; nf < 4; ++nf) bv[nf] = bias[col0 + wc * 64 + nf * 16 + ln15];

    if (EPI == 2) {
        // W interleaved by 16-col blocks: nf=2p -> s, nf=2p+1 -> t, same j.
        const float2* zin2 = (const float2*)zin;
        float2*       out2 = (float2*)outf;
#pragma unroll
        for (int mi = 0; mi < 4; ++mi) {
#pragma unroll
            for (int r = 0; r < 4; ++r) {
                const size_t row = row0 + wr * 64 + mi * 16 + lq * 4 + r;
                float sv = 0.f;
#pragma unroll
                for (int p = 0; p < 2; ++p) {
                    float s = acc[mi][2 * p][r] + bv[2 * p];
                    float t = acc[mi][2 * p + 1][r] + bv[2 * p + 1];
                    const size_t j = (col0 >> 1) + wc * 32 + p * 16 + ln15;
                    float2 zv = zin2[row * 512 + j];
                    float2 o; o.x = zv.x; o.y = zv.y * __expf(s) + t;
                    out2[row * 512 + j] = o;
                    sv += s;
                }
                sv += __shfl_xor(sv, 1, 64);
                sv += __shfl_xor(sv, 2, 64);
                sv += __shfl_xor(sv, 4, 64);
                sv += __shfl_xor(sv, 8, 64);
                if (ln15 == 0) atomicAdd(&ldout[row], sv);
            }
        }
    } else {
#pragma unroll
        for (int mi = 0; mi < 4; ++mi) {
#pragma unroll
            for (int r = 0; r < 4; ++r) {
                const size_t row = row0 + wr * 64 + mi * 16 + lq * 4 + r;
#pragma unroll
                for (int nf = 0; nf < 4; ++nf) {
                    const size_t col = col0 + wc * 64 + nf * 16 + ln15;
                    float v = acc[mi][nf][r] + bv[nf];
                    if (EPI == 0) {
                        float g = 0.5f * v * (1.0f + erff(v * 0.70710678118654752f));
                        outb[row * N + col] = f2bf(g);
                    } else {
                        outf[row * N + col] = v;
                    }
                }
            }
        }
    }
}

// One fused prep pass: W1/W2 cvt, W3 interleave-by-16 cvt, pack_even, b3i, ldout.
__global__ void prep_all(const float* __restrict__ W1, const float* __restrict__ W2,
                         const float* __restrict__ W3, const float* __restrict__ b3,
                         const float* __restrict__ z,  const float* __restrict__ ld,
                         unsigned short* __restrict__ w1b, unsigned short* __restrict__ w2b,
                         unsigned short* __restrict__ w3i, float* __restrict__ b3i,
                         unsigned short* __restrict__ zm,  float* __restrict__ ldout)
{
    constexpr int N1 = 2048 * 512 / 4;
    constexpr int N2 = 2048 * 2048 / 4;
    constexpr int N3 = 1024 * 2048 / 4;
    constexpr int N4 = 16384 * 1024 / 4;
    constexpr int N5 = 1024;
    constexpr int N6 = 16384;
    constexpr int TOT = N1 + N2 + N3 + N4 + N5 + N6;
    const int stride = gridDim.x * blockDim.x;
    for (int i = blockIdx.x * blockDim.x + threadIdx.x; i < TOT; i += stride) {
        int j = i;
        if (j < N1) {
            float4 v = ((const float4*)W1)[j];
            ((us4*)w1b)[j] = us4{ f2bf(v.x), f2bf(v.y), f2bf(v.z), f2bf(v.w) };
            continue;
        }
        j -= N1;
        if (j < N2) {
            float4 v = ((const float4*)W2)[j];
            ((us4*)w2b)[j] = us4{ f2bf(v.x), f2bf(v.y), f2bf(v.z), f2bf(v.w) };
            continue;
        }
        j -= N2;
        if (j < N3) {
            int row = j >> 9, c4 = j & 511;
            int q = row >> 5, u = row & 31;
            int srcrow = (u < 16) ? (q * 16 + u) : (512 + q * 16 + u - 16);
            float4 v = ((const float4*)W3)[(size_t)srcrow * 512 + c4];
            ((us4*)w3i)[j] = us4{ f2bf(v.x), f2bf(v.y), f2bf(v.z), f2bf(v.w) };
            continue;
        }
        j -= N3;
        if (j < N4) {
            float4 v = ((const float4*)z)[j];
            ((us2*)zm)[j] = us2{ f2bf(v.x), f2bf(v.z) };
            continue;
        }
        j -= N4;
        if (j < N5) {
            int q = j >> 5, u = j & 31;
            b3i[j] = b3[(u < 16) ? (q * 16 + u) : (512 + q * 16 + u - 16)];
            continue;
        }
        j -= N5;
        ldout[j] = ld[j];
    }
}

extern "C" void kernel_launch(void* const* d_in, const int* in_sizes, int n_in,
                              void* d_out, int out_size, void* d_ws, size_t ws_size,
                              hipStream_t stream)
{
    const float* z  = (const float*)d_in[0];
    const float* ld = (const float*)d_in[1];
    const float* W1 = (const float*)d_in[2];
    const float* b1 = (const float*)d_in[3];
    const float* W2 = (const float*)d_in[4];
    const float* b2 = (const float*)d_in[5];
    const float* W3 = (const float*)d_in[6];
    const float* b3 = (const float*)d_in[7];

    float* out   = (float*)d_out;
    float* zout  = out;
    float* ldout = out + (size_t)16384 * 1024;

    char* w = (char*)d_ws;
    unsigned short* zm  = (unsigned short*)w; w += (size_t)16384 * 512 * 2;
    unsigned short* w1b = (unsigned short*)w; w += (size_t)2048 * 512 * 2;
    unsigned short* w2b = (unsigned short*)w; w += (size_t)2048 * 2048 * 2;
    unsigned short* w3i = (unsigned short*)w; w += (size_t)1024 * 2048 * 2;
    unsigned short* h1  = (unsigned short*)w; w += (size_t)16384 * 2048 * 2;
    unsigned short* h2  = (unsigned short*)w; w += (size_t)16384 * 2048 * 2;
    float*          b3i = (float*)w;          w += 1024 * 4;

    (void)hipFuncSetAttribute((const void*)&gemm256<0, 512,  2048>,
                              hipFuncAttributeMaxDynamicSharedMemorySize, 131072);
    (void)hipFuncSetAttribute((const void*)&gemm256<0, 2048, 2048>,
                              hipFuncAttributeMaxDynamicSharedMemorySize, 131072);
    (void)hipFuncSetAttribute((const void*)&gemm256<2, 2048, 1024>,
                              hipFuncAttributeMaxDynamicSharedMemorySize, 131072);

    prep_all<<<2048, 256, 0, stream>>>(W1, W2, W3, b3, z, ld,
                                       w1b, w2b, w3i, b3i, zm, ldout);

    gemm256<0, 512,  2048><<<dim3(8, 64), 1024, 131072, stream>>>(zm, w1b, b1, h1, nullptr, nullptr, nullptr);
    gemm256<0, 2048, 2048><<<dim3(8, 64), 1024, 131072, stream>>>(h1, w2b, b2, h2, nullptr, nullptr, nullptr);
    gemm256<2, 2048, 1024><<<dim3(4, 64), 1024, 131072, stream>>>(h2, w3i, b3i, nullptr, zout, z, ldout);
}

// Round 25
// 277.753 us; speedup vs baseline: 1.2335x; 1.0499x over previous
//
#include <hip/hip_runtime.h>
#include <hip/hip_bf16.h>
#include <cstdint>

typedef __bf16 bf16x8 __attribute__((ext_vector_type(8)));
typedef float  f32x4  __attribute__((ext_vector_type(4)));

struct alignas(4) us2 { unsigned short x, y; };
struct alignas(8) us4 { unsigned short x, y, z, w; };

__device__ __forceinline__ unsigned short f2bf(float f) {
    union { float f; unsigned u; } a; a.f = f;
    unsigned r = a.u + 0x7fffu + ((a.u >> 16) & 1u);   // round-to-nearest-even
    return (unsigned short)(r >> 16);
}

__device__ __forceinline__ void gl_lds16(const void* g, void* s) {
    __builtin_amdgcn_global_load_lds(
        (const __attribute__((address_space(1))) void*)g,
        (__attribute__((address_space(3))) void*)s, 16, 0, 0);
}

#define SCHEDB()  __builtin_amdgcn_sched_barrier(0)
#define SBAR()    do { SCHEDB(); __builtin_amdgcn_s_barrier(); SCHEDB(); } while (0)
#define WAITLG(N) do { asm volatile("s_waitcnt lgkmcnt(" #N ")" ::: "memory"); SCHEDB(); } while (0)
#define WAITVM(N) do { asm volatile("s_waitcnt vmcnt(" #N ")" ::: "memory"); SCHEDB(); } while (0)

// C = A(MxK) @ W(NxK)^T, bf16 in, fp32 acc. 256x256 tile.
// R25 = R24 (best: 291.6us, GEMM2 139.5us, MfmaUtil 46.3%, Occ 42.6%) with the
// per-half body MERGED: 8 ds_reads -> stage -> single WAITLG(0) -> one 16-MFMA
// cluster. Rationale: at 4 waves/SIMD, TLP covers read latency; the R24 2-group
// split (WAITLG(2)+extra setprio pair) was a 2-wave-ILP vestige costing sync
// instructions and breaking the MFMA burst. Zero register cost (budget is
// 120/128 per wave - any prefetch set would drop occupancy to 3 waves/SIMD).
// 1024 threads / 16 waves (4Mx4N), wave-tile 64x64, acc[4][4] (64 AGPR).
// Ring of 4 K-32 half-slots (A 16KB + B 16KB, 128KB). Stage h+3 during h
// (2 gl_lds per thread per half). Ladder WAITVM(4/2/0) counted.
// Swizzle: R3-proven row-bits[2:1] XOR (0 conflicts measured).
// EPI 0: outb = bf16(gelu_exact(acc+bias)) ; EPI 1: outf = acc+bias ;
// EPI 2: fused coupling, W3 interleaved by 16-col blocks (s-block | t-block).
template<int EPI, int K, int N>
__global__ __launch_bounds__(1024)
void gemm256(const unsigned short* __restrict__ A,
             const unsigned short* __restrict__ W,
             const float* __restrict__ bias,
             unsigned short* __restrict__ outb,
             float* __restrict__ outf,
             const float* __restrict__ zin,
             float* __restrict__ ldout)
{
    extern __shared__ char smem[];
    constexpr int NH = K / 32;           // number of K-32 halves (16 or 64)
    constexpr int GX = N / 256;

    const int tid  = threadIdx.x;
    const int lane = tid & 63;
    const int wv   = tid >> 6;           // 0..15
    const int wr   = wv >> 2, wc = wv & 3;

    // T1: bijective XCD swizzle (nwg divisible by 8 for all our shapes)
    const int bid = blockIdx.y * GX + blockIdx.x;
    const int nwg = GX * (int)gridDim.y;
    const int swz = (bid & 7) * (nwg >> 3) + (bid >> 3);
    const size_t row0 = (size_t)(swz / GX) * 256;
    const size_t col0 = (size_t)(swz % GX) * 256;

    // LDS: A ring = 4 x 16KB at +0 ; B ring = 4 x 16KB at +65536.
    // Half-slot: 256 rows x 64B. Chunk c (16B): row c>>2, pos c&3, holds
    // src k-chunk (c&3) ^ ((row>>1)&3)   [R3 swizzle, 0-conflict]
    const int cse = (((tid & 3) ^ ((tid >> 3) & 3)) << 3);  // src elem offset
    const unsigned short* ag = A + (row0 + (tid >> 2)) * (size_t)K + cse;
    const unsigned short* bg = W + (col0 + (tid >> 2)) * (size_t)K + cse;

    auto stage = [&](int hh) {           // 2 x gl_lds (full A + B half-slots)
        char* dA = smem + (hh & 3) * 16384 + tid * 16;
        char* dB = dA + 65536;
        gl_lds16(ag + (size_t)hh * 32, dA);
        gl_lds16(bg + (size_t)hh * 32, dB);
    };

    // fragment reads: byte = row*64 + ((lane>>4) ^ ((row>>1)&3))*16
    const int ln15 = lane & 15;
    const int xo   = (((lane >> 4) ^ ((ln15 >> 1) & 3)) << 4);
    const int arow = wr * 64 + ln15;                        // + mi*16 (mi 0..3)
    const int brow = wc * 64 + ln15;                        // + nf*16 (nf 0..3)

#define LD(base, row) (*(const bf16x8*)((base) + (size_t)(row) * 64 + xo))

    f32x4 acc[4][4] = {};

    // prologue: stage halves 0,1,2 (6 loads in flight)
    stage(0); stage(1); stage(2);

    for (int h = 0; h < NH; ++h) {
        const char* cA = smem + (h & 3) * 16384;
        const char* cB = cA + 65536;

        // top-of-half: certify stage(h) (counted; leaves h+1,h+2 in flight)
        if (h <= NH - 3)      WAITVM(4);
        else if (h == NH - 2) WAITVM(2);
        else                  WAITVM(0);
        SBAR();

        bf16x8 aF[4], bF[4];
#pragma unroll
        for (int mf = 0; mf < 4; ++mf) aF[mf] = LD(cA, arow + mf * 16);
#pragma unroll
        for (int nf = 0; nf < 4; ++nf) bF[nf] = LD(cB, brow + nf * 16);
        SCHEDB();
        if (h + 3 < NH) stage(h + 3);

        WAITLG(0);                       // all 8 operands certified
        __builtin_amdgcn_s_setprio(1);
#pragma unroll
        for (int mf = 0; mf < 4; ++mf)
#pragma unroll
            for (int nf = 0; nf < 4; ++nf)
                acc[mf][nf] = __builtin_amdgcn_mfma_f32_16x16x32_bf16(
                    aF[mf], bF[nf], acc[mf][nf], 0, 0, 0);
        __builtin_amdgcn_s_setprio(0);
    }
#undef LD

    // epilogue: D layout col = lane&15, row = (lane>>4)*4 + reg
    const int lq = lane >> 4;
    float bv[4];
#pragma unroll
    for (int nf = 0; nf < 4; ++nf) bv[nf] = bias[col0 + wc * 64 + nf * 16 + ln15];

    if (EPI == 2) {
        // W interleaved by 16-col blocks: nf=2p -> s, nf=2p+1 -> t, same j.
        const float2* zin2 = (const float2*)zin;
        float2*       out2 = (float2*)outf;
#pragma unroll
        for (int mi = 0; mi < 4; ++mi) {
#pragma unroll
            for (int r = 0; r < 4; ++r) {
                const size_t row = row0 + wr * 64 + mi * 16 + lq * 4 + r;
                float sv = 0.f;
#pragma unroll
                for (int p = 0; p < 2; ++p) {
                    float s = acc[mi][2 * p][r] + bv[2 * p];
                    float t = acc[mi][2 * p + 1][r] + bv[2 * p + 1];
                    const size_t j = (col0 >> 1) + wc * 32 + p * 16 + ln15;
                    float2 zv = zin2[row * 512 + j];
                    float2 o; o.x = zv.x; o.y = zv.y * __expf(s) + t;
                    out2[row * 512 + j] = o;
                    sv += s;
                }
                sv += __shfl_xor(sv, 1, 64);
                sv += __shfl_xor(sv, 2, 64);
                sv += __shfl_xor(sv, 4, 64);
                sv += __shfl_xor(sv, 8, 64);
                if (ln15 == 0) atomicAdd(&ldout[row], sv);
            }
        }
    } else {
#pragma unroll
        for (int mi = 0; mi < 4; ++mi) {
#pragma unroll
            for (int r = 0; r < 4; ++r) {
                const size_t row = row0 + wr * 64 + mi * 16 + lq * 4 + r;
#pragma unroll
                for (int nf = 0; nf < 4; ++nf) {
                    const size_t col = col0 + wc * 64 + nf * 16 + ln15;
                    float v = acc[mi][nf][r] + bv[nf];
                    if (EPI == 0) {
                        float g = 0.5f * v * (1.0f + erff(v * 0.70710678118654752f));
                        outb[row * N + col] = f2bf(g);
                    } else {
                        outf[row * N + col] = v;
                    }
                }
            }
        }
    }
}

// One fused prep pass: W1/W2 cvt, W3 interleave-by-16 cvt, pack_even, b3i, ldout.
__global__ void prep_all(const float* __restrict__ W1, const float* __restrict__ W2,
                         const float* __restrict__ W3, const float* __restrict__ b3,
                         const float* __restrict__ z,  const float* __restrict__ ld,
                         unsigned short* __restrict__ w1b, unsigned short* __restrict__ w2b,
                         unsigned short* __restrict__ w3i, float* __restrict__ b3i,
                         unsigned short* __restrict__ zm,  float* __restrict__ ldout)
{
    constexpr int N1 = 2048 * 512 / 4;
    constexpr int N2 = 2048 * 2048 / 4;
    constexpr int N3 = 1024 * 2048 / 4;
    constexpr int N4 = 16384 * 1024 / 4;
    constexpr int N5 = 1024;
    constexpr int N6 = 16384;
    constexpr int TOT = N1 + N2 + N3 + N4 + N5 + N6;
    const int stride = gridDim.x * blockDim.x;
    for (int i = blockIdx.x * blockDim.x + threadIdx.x; i < TOT; i += stride) {
        int j = i;
        if (j < N1) {
            float4 v = ((const float4*)W1)[j];
            ((us4*)w1b)[j] = us4{ f2bf(v.x), f2bf(v.y), f2bf(v.z), f2bf(v.w) };
            continue;
        }
        j -= N1;
        if (j < N2) {
            float4 v = ((const float4*)W2)[j];
            ((us4*)w2b)[j] = us4{ f2bf(v.x), f2bf(v.y), f2bf(v.z), f2bf(v.w) };
            continue;
        }
        j -= N2;
        if (j < N3) {
            int row = j >> 9, c4 = j & 511;
            int q = row >> 5, u = row & 31;
            int srcrow = (u < 16) ? (q * 16 + u) : (512 + q * 16 + u - 16);
            float4 v = ((const float4*)W3)[(size_t)srcrow * 512 + c4];
            ((us4*)w3i)[j] = us4{ f2bf(v.x), f2bf(v.y), f2bf(v.z), f2bf(v.w) };
            continue;
        }
        j -= N3;
        if (j < N4) {
            float4 v = ((const float4*)z)[j];
            ((us2*)zm)[j] = us2{ f2bf(v.x), f2bf(v.z) };
            continue;
        }
        j -= N4;
        if (j < N5) {
            int q = j >> 5, u = j & 31;
            b3i[j] = b3[(u < 16) ? (q * 16 + u) : (512 + q * 16 + u - 16)];
            continue;
        }
        j -= N5;
        ldout[j] = ld[j];
    }
}

extern "C" void kernel_launch(void* const* d_in, const int* in_sizes, int n_in,
                              void* d_out, int out_size, void* d_ws, size_t ws_size,
                              hipStream_t stream)
{
    const float* z  = (const float*)d_in[0];
    const float* ld = (const float*)d_in[1];
    const float* W1 = (const float*)d_in[2];
    const float* b1 = (const float*)d_in[3];
    const float* W2 = (const float*)d_in[4];
    const float* b2 = (const float*)d_in[5];
    const float* W3 = (const float*)d_in[6];
    const float* b3 = (const float*)d_in[7];

    float* out   = (float*)d_out;
    float* zout  = out;
    float* ldout = out + (size_t)16384 * 1024;

    char* w = (char*)d_ws;
    unsigned short* zm  = (unsigned short*)w; w += (size_t)16384 * 512 * 2;
    unsigned short* w1b = (unsigned short*)w; w += (size_t)2048 * 512 * 2;
    unsigned short* w2b = (unsigned short*)w; w += (size_t)2048 * 2048 * 2;
    unsigned short* w3i = (unsigned short*)w; w += (size_t)1024 * 2048 * 2;
    unsigned short* h1  = (unsigned short*)w; w += (size_t)16384 * 2048 * 2;
    unsigned short* h2  = (unsigned short*)w; w += (size_t)16384 * 2048 * 2;
    float*          b3i = (float*)w;          w += 1024 * 4;

    (void)hipFuncSetAttribute((const void*)&gemm256<0, 512,  2048>,
                              hipFuncAttributeMaxDynamicSharedMemorySize, 131072);
    (void)hipFuncSetAttribute((const void*)&gemm256<0, 2048, 2048>,
                              hipFuncAttributeMaxDynamicSharedMemorySize, 131072);
    (void)hipFuncSetAttribute((const void*)&gemm256<2, 2048, 1024>,
                              hipFuncAttributeMaxDynamicSharedMemorySize, 131072);

    prep_all<<<2048, 256, 0, stream>>>(W1, W2, W3, b3, z, ld,
                                       w1b, w2b, w3i, b3i, zm, ldout);

    gemm256<0, 512,  2048><<<dim3(8, 64), 1024, 131072, stream>>>(zm, w1b, b1, h1, nullptr, nullptr, nullptr);
    gemm256<0, 2048, 2048><<<dim3(8, 64), 1024, 131072, stream>>>(h1, w2b, b2, h2, nullptr, nullptr, nullptr);
    gemm256<2, 2048, 1024><<<dim3(4, 64), 1024, 131072, stream>>>(h2, w3i, b3i, nullptr, zout, z, ldout);
}

// Round 27
// 271.767 us; speedup vs baseline: 1.2606x; 1.0220x over previous
//
#include <hip/hip_runtime.h>
#include <hip/hip_bf16.h>
#include <cstdint>

typedef __bf16 bf16x8 __attribute__((ext_vector_type(8)));
typedef float  f32x4  __attribute__((ext_vector_type(4)));

struct alignas(4) us2 { unsigned short x, y; };
struct alignas(8) us4 { unsigned short x, y, z, w; };

__device__ __forceinline__ unsigned short f2bf(float f) {
    union { float f; unsigned u; } a; a.f = f;
    unsigned r = a.u + 0x7fffu + ((a.u >> 16) & 1u);   // round-to-nearest-even
    return (unsigned short)(r >> 16);
}

__device__ __forceinline__ void gl_lds16(const void* g, void* s) {
    __builtin_amdgcn_global_load_lds(
        (const __attribute__((address_space(1))) void*)g,
        (__attribute__((address_space(3))) void*)s, 16, 0, 0);
}

#define SCHEDB()  __builtin_amdgcn_sched_barrier(0)
#define SBAR()    do { SCHEDB(); __builtin_amdgcn_s_barrier(); SCHEDB(); } while (0)
#define WAITLG(N) do { asm volatile("s_waitcnt lgkmcnt(" #N ")" ::: "memory"); SCHEDB(); } while (0)
#define WAITVM(N) do { asm volatile("s_waitcnt vmcnt(" #N ")" ::: "memory"); SCHEDB(); } while (0)

// C = A(MxK) @ W(NxK)^T, bf16 in, fp32 acc. 256x256 tile.
// R27 = R26's pre-barrier-read mechanism with the RACE FIXED: certification of
// slot h+1 is {own WAITVM -> SBAR} (block-wide), not own-WAITVM alone.
// R26 bug: vmcnt is PER-WAVE; certifying own stage(h+1) then reading slot h+1
// pre-barrier raced other waves' in-flight DMA writes (absmax 6.3e4).
// Schedule per half h:
//   WAITVM(2) [own stage(h+1) certified; ladder 2/0 at tail] -> SBAR [slots h
//   AND h+1 block-wide landed] -> WAITLG(0) [own pre-issued reads of slot h]
//   -> setprio(1) 16 MFMA setprio(0) -> stage(h+3) -> issue 8 reads of slot
//   h+1 (race-free: h+1 block-certified at this half's barrier; reuse safe:
//   stage(h+5) issues only after top-of-h+2 barrier, reads certified by then).
// Prologue: stage 0,1,2 -> WAITVM(4) -> SBAR -> read slot 0.
// 1024 threads / 16 waves (4Mx4N), wave-tile 64x64, acc[4][4] (64 AGPR),
// 4 waves/SIMD (TLP covers latency; reg budget 120/128 - no prefetch sets).
// Ring of 4 K-32 half-slots (A 16KB + B 16KB, 128KB). Stage h+3 during h.
// Swizzle: R3-proven row-bits[2:1] XOR (0 conflicts measured).
// EPI 0: outb = bf16(gelu_exact(acc+bias)) ; EPI 1: outf = acc+bias ;
// EPI 2: fused coupling, W3 interleaved by 16-col blocks (s-block | t-block).
template<int EPI, int K, int N>
__global__ __launch_bounds__(1024)
void gemm256(const unsigned short* __restrict__ A,
             const unsigned short* __restrict__ W,
             const float* __restrict__ bias,
             unsigned short* __restrict__ outb,
             float* __restrict__ outf,
             const float* __restrict__ zin,
             float* __restrict__ ldout)
{
    extern __shared__ char smem[];
    constexpr int NH = K / 32;           // number of K-32 halves (16 or 64)
    constexpr int GX = N / 256;

    const int tid  = threadIdx.x;
    const int lane = tid & 63;
    const int wv   = tid >> 6;           // 0..15
    const int wr   = wv >> 2, wc = wv & 3;

    // T1: bijective XCD swizzle (nwg divisible by 8 for all our shapes)
    const int bid = blockIdx.y * GX + blockIdx.x;
    const int nwg = GX * (int)gridDim.y;
    const int swz = (bid & 7) * (nwg >> 3) + (bid >> 3);
    const size_t row0 = (size_t)(swz / GX) * 256;
    const size_t col0 = (size_t)(swz % GX) * 256;

    // LDS: A ring = 4 x 16KB at +0 ; B ring = 4 x 16KB at +65536.
    // Half-slot: 256 rows x 64B. Chunk c (16B): row c>>2, pos c&3, holds
    // src k-chunk (c&3) ^ ((row>>1)&3)   [R3 swizzle, 0-conflict]
    const int cse = (((tid & 3) ^ ((tid >> 3) & 3)) << 3);  // src elem offset
    const unsigned short* ag = A + (row0 + (tid >> 2)) * (size_t)K + cse;
    const unsigned short* bg = W + (col0 + (tid >> 2)) * (size_t)K + cse;

    auto stage = [&](int hh) {           // 2 x gl_lds (full A + B half-slots)
        char* dA = smem + (hh & 3) * 16384 + tid * 16;
        char* dB = dA + 65536;
        gl_lds16(ag + (size_t)hh * 32, dA);
        gl_lds16(bg + (size_t)hh * 32, dB);
    };

    // fragment reads: byte = row*64 + ((lane>>4) ^ ((row>>1)&3))*16
    const int ln15 = lane & 15;
    const int xo   = (((lane >> 4) ^ ((ln15 >> 1) & 3)) << 4);
    const int arow = wr * 64 + ln15;                        // + mi*16 (mi 0..3)
    const int brow = wc * 64 + ln15;                        // + nf*16 (nf 0..3)

#define LD(base, row) (*(const bf16x8*)((base) + (size_t)(row) * 64 + xo))

    f32x4 acc[4][4] = {};
    bf16x8 aF[4], bF[4];

    // prologue: stage 0,1,2 -> own cert of stage(0) -> BARRIER (block-wide)
    // -> issue slot-0 reads (certified data; reads float across next barrier)
    stage(0); stage(1); stage(2);
    WAITVM(4);                           // own stage(0) landed (1,2 in flight)
    SBAR();                              // block-wide: slot 0 landed
#pragma unroll
    for (int mf = 0; mf < 4; ++mf) aF[mf] = LD(smem, arow + mf * 16);
#pragma unroll
    for (int nf = 0; nf < 4; ++nf) bF[nf] = LD(smem + 65536, brow + nf * 16);

    for (int h = 0; h < NH; ++h) {
        // pre-barrier: certify OWN stage(h+1); barrier makes it block-wide.
        // outstanding here = stage(h+1),stage(h+2) = 4 loads (h+3 not yet issued)
        if (h <= NH - 3) WAITVM(2);
        else             WAITVM(0);
        SBAR();                          // slots h, h+1 block-wide landed

        WAITLG(0);                       // own pre-issued reads of slot h
        __builtin_amdgcn_s_setprio(1);
#pragma unroll
        for (int mf = 0; mf < 4; ++mf)
#pragma unroll
            for (int nf = 0; nf < 4; ++nf)
                acc[mf][nf] = __builtin_amdgcn_mfma_f32_16x16x32_bf16(
                    aF[mf], bF[nf], acc[mf][nf], 0, 0, 0);
        __builtin_amdgcn_s_setprio(0);

        if (h + 3 < NH) stage(h + 3);
        if (h + 1 < NH) {                // pre-barrier reads of slot h+1
            const char* cA = smem + ((h + 1) & 3) * 16384;
            const char* cB = cA + 65536;
#pragma unroll
            for (int mf = 0; mf < 4; ++mf) aF[mf] = LD(cA, arow + mf * 16);
#pragma unroll
            for (int nf = 0; nf < 4; ++nf) bF[nf] = LD(cB, brow + nf * 16);
            SCHEDB();
        }
    }
#undef LD

    // epilogue: D layout col = lane&15, row = (lane>>4)*4 + reg
    const int lq = lane >> 4;
    float bv[4];
#pragma unroll
    for (int nf = 0; nf < 4; ++nf) bv[nf] = bias[col0 + wc * 64 + nf * 16 + ln15];

    if (EPI == 2) {
        // W interleaved by 16-col blocks: nf=2p -> s, nf=2p+1 -> t, same j.
        const float2* zin2 = (const float2*)zin;
        float2*       out2 = (float2*)outf;
#pragma unroll
        for (int mi = 0; mi < 4; ++mi) {
#pragma unroll
            for (int r = 0; r < 4; ++r) {
                const size_t row = row0 + wr * 64 + mi * 16 + lq * 4 + r;
                float sv = 0.f;
#pragma unroll
                for (int p = 0; p < 2; ++p) {
                    float s = acc[mi][2 * p][r] + bv[2 * p];
                    float t = acc[mi][2 * p + 1][r] + bv[2 * p + 1];
                    const size_t j = (col0 >> 1) + wc * 32 + p * 16 + ln15;
                    float2 zv = zin2[row * 512 + j];
                    float2 o; o.x = zv.x; o.y = zv.y * __expf(s) + t;
                    out2[row * 512 + j] = o;
                    sv += s;
                }
                sv += __shfl_xor(sv, 1, 64);
                sv += __shfl_xor(sv, 2, 64);
                sv += __shfl_xor(sv, 4, 64);
                sv += __shfl_xor(sv, 8, 64);
                if (ln15 == 0) atomicAdd(&ldout[row], sv);
            }
        }
    } else {
#pragma unroll
        for (int mi = 0; mi < 4; ++mi) {
#pragma unroll
            for (int r = 0; r < 4; ++r) {
                const size_t row = row0 + wr * 64 + mi * 16 + lq * 4 + r;
#pragma unroll
                for (int nf = 0; nf < 4; ++nf) {
                    const size_t col = col0 + wc * 64 + nf * 16 + ln15;
                    float v = acc[mi][nf][r] + bv[nf];
                    if (EPI == 0) {
                        float g = 0.5f * v * (1.0f + erff(v * 0.70710678118654752f));
                        outb[row * N + col] = f2bf(g);
                    } else {
                        outf[row * N + col] = v;
                    }
                }
            }
        }
    }
}

// One fused prep pass: W1/W2 cvt, W3 interleave-by-16 cvt, pack_even, b3i, ldout.
__global__ void prep_all(const float* __restrict__ W1, const float* __restrict__ W2,
                         const float* __restrict__ W3, const float* __restrict__ b3,
                         const float* __restrict__ z,  const float* __restrict__ ld,
                         unsigned short* __restrict__ w1b, unsigned short* __restrict__ w2b,
                         unsigned short* __restrict__ w3i, float* __restrict__ b3i,
                         unsigned short* __restrict__ zm,  float* __restrict__ ldout)
{
    constexpr int N1 = 2048 * 512 / 4;
    constexpr int N2 = 2048 * 2048 / 4;
    constexpr int N3 = 1024 * 2048 / 4;
    constexpr int N4 = 16384 * 1024 / 4;
    constexpr int N5 = 1024;
    constexpr int N6 = 16384;
    constexpr int TOT = N1 + N2 + N3 + N4 + N5 + N6;
    const int stride = gridDim.x * blockDim.x;
    for (int i = blockIdx.x * blockDim.x + threadIdx.x; i < TOT; i += stride) {
        int j = i;
        if (j < N1) {
            float4 v = ((const float4*)W1)[j];
            ((us4*)w1b)[j] = us4{ f2bf(v.x), f2bf(v.y), f2bf(v.z), f2bf(v.w) };
            continue;
        }
        j -= N1;
        if (j < N2) {
            float4 v = ((const float4*)W2)[j];
            ((us4*)w2b)[j] = us4{ f2bf(v.x), f2bf(v.y), f2bf(v.z), f2bf(v.w) };
            continue;
        }
        j -= N2;
        if (j < N3) {
            int row = j >> 9, c4 = j & 511;
            int q = row >> 5, u = row & 31;
            int srcrow = (u < 16) ? (q * 16 + u) : (512 + q * 16 + u - 16);
            float4 v = ((const float4*)W3)[(size_t)srcrow * 512 + c4];
            ((us4*)w3i)[j] = us4{ f2bf(v.x), f2bf(v.y), f2bf(v.z), f2bf(v.w) };
            continue;
        }
        j -= N3;
        if (j < N4) {
            float4 v = ((const float4*)z)[j];
            ((us2*)zm)[j] = us2{ f2bf(v.x), f2bf(v.z) };
            continue;
        }
        j -= N4;
        if (j < N5) {
            int q = j >> 5, u = j & 31;
            b3i[j] = b3[(u < 16) ? (q * 16 + u) : (512 + q * 16 + u - 16)];
            continue;
        }
        j -= N5;
        ldout[j] = ld[j];
    }
}

extern "C" void kernel_launch(void* const* d_in, const int* in_sizes, int n_in,
                              void* d_out, int out_size, void* d_ws, size_t ws_size,
                              hipStream_t stream)
{
    const float* z  = (const float*)d_in[0];
    const float* ld = (const float*)d_in[1];
    const float* W1 = (const float*)d_in[2];
    const float* b1 = (const float*)d_in[3];
    const float* W2 = (const float*)d_in[4];
    const float* b2 = (const float*)d_in[5];
    const float* W3 = (const float*)d_in[6];
    const float* b3 = (const float*)d_in[7];

    float* out   = (float*)d_out;
    float* zout  = out;
    float* ldout = out + (size_t)16384 * 1024;

    char* w = (char*)d_ws;
    unsigned short* zm  = (unsigned short*)w; w += (size_t)16384 * 512 * 2;
    unsigned short* w1b = (unsigned short*)w; w += (size_t)2048 * 512 * 2;
    unsigned short* w2b = (unsigned short*)w; w += (size_t)2048 * 2048 * 2;
    unsigned short* w3i = (unsigned short*)w; w += (size_t)1024 * 2048 * 2;
    unsigned short* h1  = (unsigned short*)w; w += (size_t)16384 * 2048 * 2;
    unsigned short* h2  = (unsigned short*)w; w += (size_t)16384 * 2048 * 2;
    float*          b3i = (float*)w;          w += 1024 * 4;

    (void)hipFuncSetAttribute((const void*)&gemm256<0, 512,  2048>,
                              hipFuncAttributeMaxDynamicSharedMemorySize, 131072);
    (void)hipFuncSetAttribute((const void*)&gemm256<0, 2048, 2048>,
                              hipFuncAttributeMaxDynamicSharedMemorySize, 131072);
    (void)hipFuncSetAttribute((const void*)&gemm256<2, 2048, 1024>,
                              hipFuncAttributeMaxDynamicSharedMemorySize, 131072);

    prep_all<<<2048, 256, 0, stream>>>(W1, W2, W3, b3, z, ld,
                                       w1b, w2b, w3i, b3i, zm, ldout);

    gemm256<0, 512,  2048><<<dim3(8, 64), 1024, 131072, stream>>>(zm, w1b, b1, h1, nullptr, nullptr, nullptr);
    gemm256<0, 2048, 2048><<<dim3(8, 64), 1024, 131072, stream>>>(h1, w2b, b2, h2, nullptr, nullptr, nullptr);
    gemm256<2, 2048, 1024><<<dim3(4, 64), 1024, 131072, stream>>>(h2, w3i, b3i, nullptr, zout, z, ldout);
}

// Round 28
// 271.663 us; speedup vs baseline: 1.2611x; 1.0004x over previous
//
#include <hip/hip_runtime.h>
#include <hip/hip_bf16.h>
#include <cstdint>

typedef __bf16 bf16x8 __attribute__((ext_vector_type(8)));
typedef float  f32x4  __attribute__((ext_vector_type(4)));

struct alignas(4) us2 { unsigned short x, y; };
struct alignas(8) us4 { unsigned short x, y, z, w; };

__device__ __forceinline__ unsigned short f2bf(float f) {
    union { float f; unsigned u; } a; a.f = f;
    unsigned r = a.u + 0x7fffu + ((a.u >> 16) & 1u);   // round-to-nearest-even
    return (unsigned short)(r >> 16);
}

__device__ __forceinline__ void gl_lds16(const void* g, void* s) {
    __builtin_amdgcn_global_load_lds(
        (const __attribute__((address_space(1))) void*)g,
        (__attribute__((address_space(3))) void*)s, 16, 0, 0);
}

#define SCHEDB()  __builtin_amdgcn_sched_barrier(0)
#define SBAR()    do { SCHEDB(); __builtin_amdgcn_s_barrier(); SCHEDB(); } while (0)
#define WAITLG(N) do { asm volatile("s_waitcnt lgkmcnt(" #N ")" ::: "memory"); SCHEDB(); } while (0)
#define WAITVM(N) do { asm volatile("s_waitcnt vmcnt(" #N ")" ::: "memory"); SCHEDB(); } while (0)

// C = A(MxK) @ W(NxK)^T, bf16 in, fp32 acc. 256x256 tile.
// R28 = R27 (best: 271.8us, MfmaUtil 50.0%, Occ 42%) + INTERLEAVED READS:
// the slot-(h+1) read of aF[mf] issues right after its 4-MFMA group (register
// dead; WAR dep - compiler may rename+hoist, ~4 spare regs available). B reads
// stay post-cluster (bF live to the end). Spreads the per-wave 8-read burst
// through the MFMA cluster -> LDS and matrix pipes co-occupied instead of the
// R27 post-cluster read clump (16 waves' bursts colliding while MFMA drains).
// Certification unchanged from R27 (race-free): reads of slot h+1 issue only
// after top-of-h {own WAITVM(2) -> SBAR} block-certified slot h+1; reuse safe
// (stage(h+5) >= 2 barriers later; reads WAITLG-certified at top of h+1).
// 1024 threads / 16 waves (4Mx4N), wave-tile 64x64, acc[4][4] (64 AGPR),
// 4 waves/SIMD. Ring of 4 K-32 half-slots (A 16KB + B 16KB, 128KB).
// Stage h+3 during h. Swizzle: R3-proven row-bits[2:1] XOR (0 conflicts).
// EPI 0: outb = bf16(gelu_exact(acc+bias)) ; EPI 1: outf = acc+bias ;
// EPI 2: fused coupling, W3 interleaved by 16-col blocks (s-block | t-block).
template<int EPI, int K, int N>
__global__ __launch_bounds__(1024)
void gemm256(const unsigned short* __restrict__ A,
             const unsigned short* __restrict__ W,
             const float* __restrict__ bias,
             unsigned short* __restrict__ outb,
             float* __restrict__ outf,
             const float* __restrict__ zin,
             float* __restrict__ ldout)
{
    extern __shared__ char smem[];
    constexpr int NH = K / 32;           // number of K-32 halves (16 or 64)
    constexpr int GX = N / 256;

    const int tid  = threadIdx.x;
    const int lane = tid & 63;
    const int wv   = tid >> 6;           // 0..15
    const int wr   = wv >> 2, wc = wv & 3;

    // T1: bijective XCD swizzle (nwg divisible by 8 for all our shapes)
    const int bid = blockIdx.y * GX + blockIdx.x;
    const int nwg = GX * (int)gridDim.y;
    const int swz = (bid & 7) * (nwg >> 3) + (bid >> 3);
    const size_t row0 = (size_t)(swz / GX) * 256;
    const size_t col0 = (size_t)(swz % GX) * 256;

    // LDS: A ring = 4 x 16KB at +0 ; B ring = 4 x 16KB at +65536.
    // Half-slot: 256 rows x 64B. Chunk c (16B): row c>>2, pos c&3, holds
    // src k-chunk (c&3) ^ ((row>>1)&3)   [R3 swizzle, 0-conflict]
    const int cse = (((tid & 3) ^ ((tid >> 3) & 3)) << 3);  // src elem offset
    const unsigned short* ag = A + (row0 + (tid >> 2)) * (size_t)K + cse;
    const unsigned short* bg = W + (col0 + (tid >> 2)) * (size_t)K + cse;

    auto stage = [&](int hh) {           // 2 x gl_lds (full A + B half-slots)
        char* dA = smem + (hh & 3) * 16384 + tid * 16;
        char* dB = dA + 65536;
        gl_lds16(ag + (size_t)hh * 32, dA);
        gl_lds16(bg + (size_t)hh * 32, dB);
    };

    // fragment reads: byte = row*64 + ((lane>>4) ^ ((row>>1)&3))*16
    const int ln15 = lane & 15;
    const int xo   = (((lane >> 4) ^ ((ln15 >> 1) & 3)) << 4);
    const int arow = wr * 64 + ln15;                        // + mi*16 (mi 0..3)
    const int brow = wc * 64 + ln15;                        // + nf*16 (nf 0..3)

#define LD(base, row) (*(const bf16x8*)((base) + (size_t)(row) * 64 + xo))

    f32x4 acc[4][4] = {};
    bf16x8 aF[4], bF[4];

    // prologue: stage 0,1,2 -> own cert of stage(0) -> BARRIER (block-wide)
    // -> issue slot-0 reads (certified data; reads float across next barrier)
    stage(0); stage(1); stage(2);
    WAITVM(4);                           // own stage(0) landed (1,2 in flight)
    SBAR();                              // block-wide: slot 0 landed
#pragma unroll
    for (int mf = 0; mf < 4; ++mf) aF[mf] = LD(smem, arow + mf * 16);
#pragma unroll
    for (int nf = 0; nf < 4; ++nf) bF[nf] = LD(smem + 65536, brow + nf * 16);

    for (int h = 0; h < NH; ++h) {
        // pre-barrier: certify OWN stage(h+1); barrier makes it block-wide.
        if (h <= NH - 3) WAITVM(2);
        else             WAITVM(0);
        SBAR();                          // slots h, h+1 block-wide landed

        WAITLG(0);                       // own pre-issued reads of slot h
        const bool more = (h + 1 < NH);
        const char* cAn = smem + ((h + 1) & 3) * 16384;
        const char* cBn = cAn + 65536;

        __builtin_amdgcn_s_setprio(1);
#pragma unroll
        for (int mf = 0; mf < 4; ++mf) {
#pragma unroll
            for (int nf = 0; nf < 4; ++nf)
                acc[mf][nf] = __builtin_amdgcn_mfma_f32_16x16x32_bf16(
                    aF[mf], bF[nf], acc[mf][nf], 0, 0, 0);
            if (more) aF[mf] = LD(cAn, arow + mf * 16);   // reg dead; interleave
        }
        __builtin_amdgcn_s_setprio(0);

        if (h + 3 < NH) stage(h + 3);
        if (more) {                      // B reads post-cluster (bF live above)
#pragma unroll
            for (int nf = 0; nf < 4; ++nf) bF[nf] = LD(cBn, brow + nf * 16);
            SCHEDB();
        }
    }
#undef LD

    // epilogue: D layout col = lane&15, row = (lane>>4)*4 + reg
    const int lq = lane >> 4;
    float bv[4];
#pragma unroll
    for (int nf = 0; nf < 4; ++nf) bv[nf] = bias[col0 + wc * 64 + nf * 16 + ln15];

    if (EPI == 2) {
        // W interleaved by 16-col blocks: nf=2p -> s, nf=2p+1 -> t, same j.
        const float2* zin2 = (const float2*)zin;
        float2*       out2 = (float2*)outf;
#pragma unroll
        for (int mi = 0; mi < 4; ++mi) {
#pragma unroll
            for (int r = 0; r < 4; ++r) {
                const size_t row = row0 + wr * 64 + mi * 16 + lq * 4 + r;
                float sv = 0.f;
#pragma unroll
                for (int p = 0; p < 2; ++p) {
                    float s = acc[mi][2 * p][r] + bv[2 * p];
                    float t = acc[mi][2 * p + 1][r] + bv[2 * p + 1];
                    const size_t j = (col0 >> 1) + wc * 32 + p * 16 + ln15;
                    float2 zv = zin2[row * 512 + j];
                    float2 o; o.x = zv.x; o.y = zv.y * __expf(s) + t;
                    out2[row * 512 + j] = o;
                    sv += s;
                }
                sv += __shfl_xor(sv, 1, 64);
                sv += __shfl_xor(sv, 2, 64);
                sv += __shfl_xor(sv, 4, 64);
                sv += __shfl_xor(sv, 8, 64);
                if (ln15 == 0) atomicAdd(&ldout[row], sv);
            }
        }
    } else {
#pragma unroll
        for (int mi = 0; mi < 4; ++mi) {
#pragma unroll
            for (int r = 0; r < 4; ++r) {
                const size_t row = row0 + wr * 64 + mi * 16 + lq * 4 + r;
#pragma unroll
                for (int nf = 0; nf < 4; ++nf) {
                    const size_t col = col0 + wc * 64 + nf * 16 + ln15;
                    float v = acc[mi][nf][r] + bv[nf];
                    if (EPI == 0) {
                        float g = 0.5f * v * (1.0f + erff(v * 0.70710678118654752f));
                        outb[row * N + col] = f2bf(g);
                    } else {
                        outf[row * N + col] = v;
                    }
                }
            }
        }
    }
}

// One fused prep pass: W1/W2 cvt, W3 interleave-by-16 cvt, pack_even, b3i, ldout.
__global__ void prep_all(const float* __restrict__ W1, const float* __restrict__ W2,
                         const float* __restrict__ W3, const float* __restrict__ b3,
                         const float* __restrict__ z,  const float* __restrict__ ld,
                         unsigned short* __restrict__ w1b, unsigned short* __restrict__ w2b,
                         unsigned short* __restrict__ w3i, float* __restrict__ b3i,
                         unsigned short* __restrict__ zm,  float* __restrict__ ldout)
{
    constexpr int N1 = 2048 * 512 / 4;
    constexpr int N2 = 2048 * 2048 / 4;
    constexpr int N3 = 1024 * 2048 / 4;
    constexpr int N4 = 16384 * 1024 / 4;
    constexpr int N5 = 1024;
    constexpr int N6 = 16384;
    constexpr int TOT = N1 + N2 + N3 + N4 + N5 + N6;
    const int stride = gridDim.x * blockDim.x;
    for (int i = blockIdx.x * blockDim.x + threadIdx.x; i < TOT; i += stride) {
        int j = i;
        if (j < N1) {
            float4 v = ((const float4*)W1)[j];
            ((us4*)w1b)[j] = us4{ f2bf(v.x), f2bf(v.y), f2bf(v.z), f2bf(v.w) };
            continue;
        }
        j -= N1;
        if (j < N2) {
            float4 v = ((const float4*)W2)[j];
            ((us4*)w2b)[j] = us4{ f2bf(v.x), f2bf(v.y), f2bf(v.z), f2bf(v.w) };
            continue;
        }
        j -= N2;
        if (j < N3) {
            int row = j >> 9, c4 = j & 511;
            int q = row >> 5, u = row & 31;
            int srcrow = (u < 16) ? (q * 16 + u) : (512 + q * 16 + u - 16);
            float4 v = ((const float4*)W3)[(size_t)srcrow * 512 + c4];
            ((us4*)w3i)[j] = us4{ f2bf(v.x), f2bf(v.y), f2bf(v.z), f2bf(v.w) };
            continue;
        }
        j -= N3;
        if (j < N4) {
            float4 v = ((const float4*)z)[j];
            ((us2*)zm)[j] = us2{ f2bf(v.x), f2bf(v.z) };
            continue;
        }
        j -= N4;
        if (j < N5) {
            int q = j >> 5, u = j & 31;
            b3i[j] = b3[(u < 16) ? (q * 16 + u) : (512 + q * 16 + u - 16)];
            continue;
        }
        j -= N5;
        ldout[j] = ld[j];
    }
}

extern "C" void kernel_launch(void* const* d_in, const int* in_sizes, int n_in,
                              void* d_out, int out_size, void* d_ws, size_t ws_size,
                              hipStream_t stream)
{
    const float* z  = (const float*)d_in[0];
    const float* ld = (const float*)d_in[1];
    const float* W1 = (const float*)d_in[2];
    const float* b1 = (const float*)d_in[3];
    const float* W2 = (const float*)d_in[4];
    const float* b2 = (const float*)d_in[5];
    const float* W3 = (const float*)d_in[6];
    const float* b3 = (const float*)d_in[7];

    float* out   = (float*)d_out;
    float* zout  = out;
    float* ldout = out + (size_t)16384 * 1024;

    char* w = (char*)d_ws;
    unsigned short* zm  = (unsigned short*)w; w += (size_t)16384 * 512 * 2;
    unsigned short* w1b = (unsigned short*)w; w += (size_t)2048 * 512 * 2;
    unsigned short* w2b = (unsigned short*)w; w += (size_t)2048 * 2048 * 2;
    unsigned short* w3i = (unsigned short*)w; w += (size_t)1024 * 2048 * 2;
    unsigned short* h1  = (unsigned short*)w; w += (size_t)16384 * 2048 * 2;
    unsigned short* h2  = (unsigned short*)w; w += (size_t)16384 * 2048 * 2;
    float*          b3i = (float*)w;          w += 1024 * 4;

    (void)hipFuncSetAttribute((const void*)&gemm256<0, 512,  2048>,
                              hipFuncAttributeMaxDynamicSharedMemorySize, 131072);
    (void)hipFuncSetAttribute((const void*)&gemm256<0, 2048, 2048>,
                              hipFuncAttributeMaxDynamicSharedMemorySize, 131072);
    (void)hipFuncSetAttribute((const void*)&gemm256<2, 2048, 1024>,
                              hipFuncAttributeMaxDynamicSharedMemorySize, 131072);

    prep_all<<<2048, 256, 0, stream>>>(W1, W2, W3, b3, z, ld,
                                       w1b, w2b, w3i, b3i, zm, ldout);

    gemm256<0, 512,  2048><<<dim3(8, 64), 1024, 131072, stream>>>(zm, w1b, b1, h1, nullptr, nullptr, nullptr);
    gemm256<0, 2048, 2048><<<dim3(8, 64), 1024, 131072, stream>>>(h1, w2b, b2, h2, nullptr, nullptr, nullptr);
    gemm256<2, 2048, 1024><<<dim3(4, 64), 1024, 131072, stream>>>(h2, w3i, b3i, nullptr, zout, z, ldout);
}